// Round 5
// baseline (124.981 us; speedup 1.0000x reference)
//
#include <hip/hip_runtime.h>
#include <stdint.h>

#define B_ 2
#define N_ 8192
#define K_ 16
#define C_ 64
#define PE_ 32
#define HID_ 16
#define GRID 1024
#define BAR_OFF (8u << 20)

typedef float f4 __attribute__((ext_vector_type(4)));

// One fused persistent kernel. 1024 blocks x 256 threads, 4 blocks/CU guaranteed:
// LDS 40448 B (<= 160K/4), VGPR capped by __launch_bounds__(256,4) -> <=128.
// P1 (blocks 0..255): ht = relu(W1 f + b1), transposed. All blocks: arrive at
// global barrier (release, agent scope -> L2 writeback), run P3 (KDE offsets,
// independent of ht) to hide barrier latency, wait flag (acquire -> cache inv),
// then P2 (neighbor max-pool over pe + gathered ht).
__global__ __launch_bounds__(256, 4) void fused_kernel(
    const float* __restrict__ p, const float* __restrict__ f,
    const float* __restrict__ pe, const float* __restrict__ W1,
    const float* __restrict__ b1, const float* __restrict__ Wpe,
    const float* __restrict__ bpe, const float* __restrict__ Wh1,
    const float* __restrict__ bh1, const float* __restrict__ Wh2,
    const float* __restrict__ bh2, const int* __restrict__ knn,
    float* __restrict__ fout, float* __restrict__ delta,
    float* __restrict__ ht, unsigned* __restrict__ bar) {
  __shared__ __align__(16) char smem[40448];
  const int t = threadIdx.x;
  const int blk = blockIdx.x;

  // ================= P1: ht (blocks 0..255, 64 points each) =================
  if (blk < 256) {
    float* sf = (float*)smem;  // [64][64]
    const int g0 = blk * 64;
    const int b = g0 >> 13;
    const int n0 = g0 & (N_ - 1);
    for (int idx = t; idx < C_ * 64; idx += 256) {
      int c = idx >> 6, nl = idx & 63;
      sf[c * 64 + nl] = f[(size_t)(b * C_ + c) * N_ + n0 + nl];
    }
    __syncthreads();
    const int nl = t & 63;
    const int q = t >> 6;  // wave id -> oc quarter (wave-uniform -> s_load W1)
    float fv[C_];
    #pragma unroll
    for (int c = 0; c < C_; ++c) fv[c] = sf[c * 64 + nl];
    float* op = ht + (size_t)(g0 + nl) * C_ + q * 16;
    #pragma unroll
    for (int o4 = 0; o4 < 4; ++o4) {
      float r[4];
      #pragma unroll
      for (int u = 0; u < 4; ++u) {
        const int oc = q * 16 + o4 * 4 + u;
        float acc = b1[oc];
        #pragma unroll
        for (int c = 0; c < C_; ++c) acc = fmaf(W1[oc * C_ + c], fv[c], acc);
        r[u] = fmaxf(acc, 0.f);
      }
      reinterpret_cast<float4*>(op)[o4] = make_float4(r[0], r[1], r[2], r[3]);
    }
  }
  // ---- arrive (release makes ht visible device-wide; last arriver sets flag)
  __syncthreads();
  if (t == 0) {
    unsigned old = __hip_atomic_fetch_add(&bar[0], 1u, __ATOMIC_ACQ_REL,
                                          __HIP_MEMORY_SCOPE_AGENT);
    if (old == GRID - 1)
      __hip_atomic_store(&bar[16], 1u, __ATOMIC_RELEASE, __HIP_MEMORY_SCOPE_AGENT);
  }

  // ================= P3: KDE offset generator (independent of ht) ===========
  {
    float* sc = (float*)smem;           // [16][48] coords
    float* spk = (float*)(smem + 3072); // [16][GSTR] pek, GSTR=584 floats
    const int g = t >> 4;
    const int i = t & 15;
    const int gid = blk * 16 + g;
    const int b = gid >> 13;

    const int idx = knn[(size_t)gid * K_ + i];
    const float* pp = p + (size_t)(b * N_ + idx) * 3;
    const float ci0 = pp[0], ci1 = pp[1], ci2 = pp[2];
    sc[g * 48 + i * 3 + 0] = ci0;
    sc[g * 48 + i * 3 + 1] = ci1;
    sc[g * 48 + i * 3 + 2] = ci2;
    __syncthreads();

    float cx[16], cy[16], cz[16];
    {
      const float4* sq = reinterpret_cast<const float4*>(&sc[g * 48]);
      #pragma unroll
      for (int j4 = 0; j4 < 4; ++j4) {
        float4 a = sq[j4 * 3 + 0], b4 = sq[j4 * 3 + 1], c4 = sq[j4 * 3 + 2];
        cx[j4 * 4 + 0] = a.x;  cy[j4 * 4 + 0] = a.y;  cz[j4 * 4 + 0] = a.z;
        cx[j4 * 4 + 1] = a.w;  cy[j4 * 4 + 1] = b4.x; cz[j4 * 4 + 1] = b4.y;
        cx[j4 * 4 + 2] = b4.z; cy[j4 * 4 + 2] = b4.w; cz[j4 * 4 + 2] = c4.x;
        cx[j4 * 4 + 3] = c4.y; cy[j4 * 4 + 3] = c4.z; cz[j4 * 4 + 3] = c4.w;
      }
    }

    // proj trick: relu(Wd.(ci-cj)+bd) = relu((Wd.ci+bd) - Wd.cj)
    #pragma unroll 1
    for (int dd = 0; dd < 2; ++dd) {
      const int d = 2 * i + dd;
      const float wx = Wpe[d * 3 + 0], wy = Wpe[d * 3 + 1], wz = Wpe[d * 3 + 2];
      const float wb = bpe[d];
      float pj[16], aa[16], pk[16];
      #pragma unroll
      for (int j = 0; j < 16; ++j) {
        pj[j] = fmaf(wx, cx[j], fmaf(wy, cy[j], wz * cz[j]));
        aa[j] = pj[j] + wb;
        pk[j] = 0.f;
      }
      #pragma unroll
      for (int j = 0; j < 16; ++j) {
        #pragma unroll
        for (int ii = 0; ii < 16; ++ii)
          pk[ii] += fmaxf(aa[ii] - pj[j], 0.f);
      }
      #pragma unroll
      for (int ii = 0; ii < 16; ++ii)
        spk[g * 584 + ii * 36 + d] = pk[ii];
    }

    const float INV2S = 0.49999975f;
    const float COEF = 0.39894225f;
    float kacc = 0.f;
    #pragma unroll
    for (int j = 0; j < 16; ++j) {
      const float dx = ci0 - cx[j], dy = ci1 - cy[j], dz = ci2 - cz[j];
      kacc += __expf(-(dx * dx + dy * dy + dz * dz) * INV2S);
    }
    const float kde = COEF * kacc;
    float m = kde;
    m = fmaxf(m, __shfl_xor(m, 1));
    m = fmaxf(m, __shfl_xor(m, 2));
    m = fmaxf(m, __shfl_xor(m, 4));
    m = fmaxf(m, __shfl_xor(m, 8));
    const float s = (kde / (m + 1e-6f)) * (1.f / 16.f);

    __syncthreads();

    float pek[PE_];
    {
      const float4* pk4 = reinterpret_cast<const float4*>(&spk[g * 584 + i * 36]);
      #pragma unroll
      for (int k = 0; k < 8; ++k) {
        float4 v = pk4[k];
        pek[4 * k + 0] = v.x * s;
        pek[4 * k + 1] = v.y * s;
        pek[4 * k + 2] = v.z * s;
        pek[4 * k + 3] = v.w * s;
      }
    }
    float o0 = bh2[0], o1 = bh2[1], o2 = bh2[2];
    #pragma unroll
    for (int hh = 0; hh < HID_; ++hh) {
      float a = bh1[hh];
      #pragma unroll
      for (int d = 0; d < PE_; ++d) a = fmaf(Wh1[hh * PE_ + d], pek[d], a);
      a = fmaxf(a, 0.f);
      o0 = fmaf(Wh2[0 * HID_ + hh], a, o0);
      o1 = fmaf(Wh2[1 * HID_ + hh], a, o1);
      o2 = fmaf(Wh2[2 * HID_ + hh], a, o2);
    }
    float* dp = delta + ((size_t)gid * K_ + i) * 3;
    dp[0] = o0;
    dp[1] = o1;
    dp[2] = o2;
  }

  // ---- wait for all P1 tiles (acquire -> invalidate caches), bounded spin
  if (t == 0) {
    unsigned it = 0;
    while (__hip_atomic_load(&bar[16], __ATOMIC_RELAXED,
                             __HIP_MEMORY_SCOPE_AGENT) == 0u) {
      __builtin_amdgcn_s_sleep(2);
      if (++it > (1u << 24)) break;  // failsafe: wrong-answer instead of hang
    }
    (void)__hip_atomic_load(&bar[16], __ATOMIC_ACQUIRE, __HIP_MEMORY_SCOPE_AGENT);
  }
  __syncthreads();

  // ================= P2: fout = max_k(pe + gathered ht), 16 points/block ====
  {
    float* sfj = (float*)smem;             // [64][128] swizzled, 32 KB
    float* sout = (float*)(smem + 32768);  // [64][20]
    const int base = blk * 16;
    const int b = base >> 13;
    const int n0b = base & (N_ - 1);
    const int lane = t & 63;
    const int w = t >> 6;                  // wave owns k-quarter w
    const int swz = lane & 31;
    const int wele = (lane >> 3) & 3;
    #pragma unroll 1
    for (int si = 0; si < 2; ++si) {
      const int n0 = n0b + si * 8;
      // phase A: gather fj -> swizzled LDS (lane = c, 256B coalesced L2 reads)
      #pragma unroll
      for (int n = 0; n < 8; ++n) {
        const int* kn = knn + (size_t)(b * N_ + n0 + n) * K_ + w * 4;  // uniform
        #pragma unroll
        for (int kk = 0; kk < 4; ++kk) {
          const int id = kn[kk];
          const float hv = ht[(size_t)(b * N_ + id) * C_ + lane];
          sfj[lane * 128 + (((n * 4 + w) ^ swz) << 2) + (kk ^ wele)] = hv;
        }
      }
      __syncthreads();
      // phase B: pe read fully coalesced (512B/half-wave), nontemporal
      const int h = lane >> 5, sl = lane & 31;
      const int n = sl >> 2, j = sl & 3;
      #pragma unroll
      for (int it2 = 0; it2 < 8; ++it2) {
        const int c = it2 * 8 + w * 2 + h;
        const int px = it2 & 3;            // == (c>>3)&3, compile-time
        const f4 pv = __builtin_nontemporal_load(
            reinterpret_cast<const f4*>(pe + ((size_t)(b * C_ + c) * N_ + n0) * K_) + sl);
        const f4 fj = *reinterpret_cast<const f4*>(&sfj[c * 128 + ((sl ^ (c & 31)) << 2)]);
        float v = fmaxf(fmaxf(pv[0] + fj[0 ^ px], pv[1] + fj[1 ^ px]),
                        fmaxf(pv[2] + fj[2 ^ px], pv[3] + fj[3 ^ px]));
        v = fmaxf(v, __shfl_xor(v, 1));
        v = fmaxf(v, __shfl_xor(v, 2));
        if (j == 0) sout[c * 20 + si * 8 + n] = v;
      }
      __syncthreads();
    }
    // fout write: full 64B rows (float4 per thread)
    const int c = t >> 2, q = t & 3;
    const float4 r = *reinterpret_cast<const float4*>(&sout[c * 20 + q * 4]);
    *reinterpret_cast<float4*>(fout + (size_t)(b * C_ + c) * N_ + n0b + q * 4) = r;
  }
}

extern "C" void kernel_launch(void* const* d_in, const int* in_sizes, int n_in,
                              void* d_out, int out_size, void* d_ws, size_t ws_size,
                              hipStream_t stream) {
  // setup_inputs() dict order: p, f, pe, W1, b1, Wpe, bpe, Wh1, bh1, Wh2, bh2, knn_idx
  const float* p   = (const float*)d_in[0];
  const float* f   = (const float*)d_in[1];
  const float* pe  = (const float*)d_in[2];
  const float* W1  = (const float*)d_in[3];
  const float* b1  = (const float*)d_in[4];
  const float* Wpe = (const float*)d_in[5];
  const float* bpe = (const float*)d_in[6];
  const float* Wh1 = (const float*)d_in[7];
  const float* bh1 = (const float*)d_in[8];
  const float* Wh2 = (const float*)d_in[9];
  const float* bh2 = (const float*)d_in[10];
  const int* knn   = (const int*)d_in[11];
  float* fout  = (float*)d_out;                        // [B,C,N]
  float* delta = (float*)d_out + (size_t)B_ * C_ * N_; // [B*N,K,3]
  float* ht = (float*)d_ws;                            // [B,N,C] = 4 MB
  unsigned* bar = (unsigned*)((char*)d_ws + BAR_OFF);  // barrier cells

  hipMemsetAsync(bar, 0, 128, stream);                 // zero cnt+flag (capturable)
  fused_kernel<<<GRID, 256, 0, stream>>>(p, f, pe, W1, b1, Wpe, bpe, Wh1, bh1,
                                         Wh2, bh2, knn, fout, delta, ht, bar);
}

// Round 6
// 84.371 us; speedup vs baseline: 1.4813x; 1.4813x over previous
//
#include <hip/hip_runtime.h>

#define B_ 2
#define N_ 8192
#define K_ 16
#define C_ 64
#define PE_ 32
#define HID_ 16

typedef float f4 __attribute__((ext_vector_type(4)));

// ---------------- Kernel 1: ht[b][n][c] = relu(sum_c' W1[c][c'] * f[b][c'][n] + b1[c])
__global__ __launch_bounds__(256) void k1_conv(
    const float* __restrict__ f, const float* __restrict__ W1,
    const float* __restrict__ b1, float* __restrict__ ht) {
  __shared__ float sf[C_ * 64];  // [c][nl]
  const int t = threadIdx.x;
  const int g0 = blockIdx.x * 64;          // flattened b*N + n base
  const int b = g0 >> 13;
  const int n0 = g0 & (N_ - 1);
  for (int idx = t; idx < C_ * 64; idx += 256) {
    int c = idx >> 6, nl = idx & 63;
    sf[c * 64 + nl] = __builtin_nontemporal_load(&f[(size_t)(b * C_ + c) * N_ + n0 + nl]);
  }
  __syncthreads();
  const int nl = t & 63;
  const int q = t >> 6;  // wave-uniform oc quarter -> W1 via s_load
  float fv[C_];
  #pragma unroll
  for (int c = 0; c < C_; ++c) fv[c] = sf[c * 64 + nl];
  float* op = ht + (size_t)(g0 + nl) * C_ + q * 16;
  #pragma unroll
  for (int o4 = 0; o4 < 4; ++o4) {
    float r[4];
    #pragma unroll
    for (int u = 0; u < 4; ++u) {
      const int oc = q * 16 + o4 * 4 + u;
      float acc = b1[oc];
      #pragma unroll
      for (int c = 0; c < C_; ++c) acc = fmaf(W1[oc * C_ + c], fv[c], acc);
      r[u] = fmaxf(acc, 0.f);
    }
    reinterpret_cast<float4*>(op)[o4] = make_float4(r[0], r[1], r[2], r[3]);
  }
}

// 16x16 in-register transpose within a 16-lane group (masks 1..8 stay in-group).
__device__ __forceinline__ void transpose16(float x[16], int l) {
  #pragma unroll
  for (int m = 1; m < 16; m <<= 1) {
    #pragma unroll
    for (int ii = 0; ii < 16; ++ii) {
      if ((ii & m) == 0) {
        const int jj = ii | m;
        const float send = (l & m) ? x[ii] : x[jj];
        const float recv = __shfl_xor(send, m);
        if (l & m) x[ii] = recv; else x[jj] = recv;
      }
    }
  }
}

// ---------------- Kernel 2+3 fused: per block = 16 points.
// P3 (KDE offsets) first: register/shuffle-resident, writes delta.
// P2 (max-pool over pe + gathered ht) second: two 8-point sub-tiles through
// 32KB swizzled LDS; disjoint LDS regions -> no barrier between P3 and P2-gather.
__global__ __launch_bounds__(256) void k23(
    const float* __restrict__ p, const float* __restrict__ pe,
    const float* __restrict__ ht, const int* __restrict__ knn,
    const float* __restrict__ Wpe, const float* __restrict__ bpe,
    const float* __restrict__ Wh1, const float* __restrict__ bh1,
    const float* __restrict__ Wh2, const float* __restrict__ bh2,
    float* __restrict__ fout, float* __restrict__ delta) {
  __shared__ __align__(16) char smem[40960];
  float* sfj = (float*)smem;                    // [64][128] swizzled, 32KB
  float* sout = (float*)(smem + 32768);         // [64][20]
  float* sc = (float*)(smem + 32768 + 5120);    // [16][48] coords
  const int t = threadIdx.x;
  const int base = blockIdx.x * 16;             // flattened b*N + n base
  const int b = base >> 13;
  const int n0b = base & (N_ - 1);

  // ================= P3: KDE offset generator =================
  {
    const int g = t >> 4, i = t & 15;
    const int gid = base + g;
    const int idx = knn[(size_t)gid * K_ + i];
    const float* pp = p + (size_t)(b * N_ + idx) * 3;
    const float ci0 = pp[0], ci1 = pp[1], ci2 = pp[2];
    sc[g * 48 + i * 3 + 0] = ci0;
    sc[g * 48 + i * 3 + 1] = ci1;
    sc[g * 48 + i * 3 + 2] = ci2;
    __syncthreads();

    const float4* sq = reinterpret_cast<const float4*>(&sc[g * 48]);
    // phase 2: lane owns d-pair {2i, 2i+1}. proj trick:
    // relu(Wd.(ci-cj)+bd) = relu((Wd.ci+bd) - Wd.cj)
    float pkA[16], pkB[16];
    #pragma unroll 1
    for (int dd = 0; dd < 2; ++dd) {
      const int d = 2 * i + dd;
      const float wx = Wpe[d * 3 + 0], wy = Wpe[d * 3 + 1], wz = Wpe[d * 3 + 2];
      const float wb = bpe[d];
      float pj[16];
      #pragma unroll
      for (int j4 = 0; j4 < 4; ++j4) {
        const float4 a = sq[j4 * 3 + 0], b4 = sq[j4 * 3 + 1], c4 = sq[j4 * 3 + 2];
        pj[4 * j4 + 0] = fmaf(wx, a.x, fmaf(wy, a.y, wz * a.z));
        pj[4 * j4 + 1] = fmaf(wx, a.w, fmaf(wy, b4.x, wz * b4.y));
        pj[4 * j4 + 2] = fmaf(wx, b4.z, fmaf(wy, b4.w, wz * c4.x));
        pj[4 * j4 + 3] = fmaf(wx, c4.y, fmaf(wy, c4.z, wz * c4.w));
      }
      float* pk = dd ? pkB : pkA;
      #pragma unroll
      for (int ii = 0; ii < 16; ++ii) pk[ii] = 0.f;
      #pragma unroll
      for (int j = 0; j < 16; ++j) {
        #pragma unroll
        for (int ii = 0; ii < 16; ++ii)
          pk[ii] += fmaxf(pj[ii] + wb - pj[j], 0.f);
      }
    }

    // kde for own point i (coords re-read from LDS, f4 walk)
    const float INV2S = 0.49999975f;
    const float COEF = 0.39894225f;
    float kacc = 0.f;
    #pragma unroll
    for (int j4 = 0; j4 < 4; ++j4) {
      const float4 a = sq[j4 * 3 + 0], b4 = sq[j4 * 3 + 1], c4 = sq[j4 * 3 + 2];
      float dx, dy, dz;
      dx = ci0 - a.x;  dy = ci1 - a.y;  dz = ci2 - a.z;
      kacc += __expf(-(dx * dx + dy * dy + dz * dz) * INV2S);
      dx = ci0 - a.w;  dy = ci1 - b4.x; dz = ci2 - b4.y;
      kacc += __expf(-(dx * dx + dy * dy + dz * dz) * INV2S);
      dx = ci0 - b4.z; dy = ci1 - b4.w; dz = ci2 - c4.x;
      kacc += __expf(-(dx * dx + dy * dy + dz * dz) * INV2S);
      dx = ci0 - c4.y; dy = ci1 - c4.z; dz = ci2 - c4.w;
      kacc += __expf(-(dx * dx + dy * dy + dz * dz) * INV2S);
    }
    const float kde = COEF * kacc;
    float m = kde;
    m = fmaxf(m, __shfl_xor(m, 1));
    m = fmaxf(m, __shfl_xor(m, 2));
    m = fmaxf(m, __shfl_xor(m, 4));
    m = fmaxf(m, __shfl_xor(m, 8));
    const float s = (kde / (m + 1e-6f)) * (1.f / 16.f);

    // 16x32 pek transpose via shuffles: after this, lane i holds point i's
    // pek[2*jj+0] = pkA[jj], pek[2*jj+1] = pkB[jj]
    transpose16(pkA, i);
    transpose16(pkB, i);

    float o0 = bh2[0], o1 = bh2[1], o2 = bh2[2];
    #pragma unroll
    for (int h = 0; h < HID_; ++h) {
      float u = 0.f;
      #pragma unroll
      for (int jj = 0; jj < 16; ++jj) {
        u = fmaf(Wh1[h * PE_ + 2 * jj + 0], pkA[jj], u);
        u = fmaf(Wh1[h * PE_ + 2 * jj + 1], pkB[jj], u);
      }
      const float a = fmaxf(fmaf(s, u, bh1[h]), 0.f);
      o0 = fmaf(Wh2[0 * HID_ + h], a, o0);
      o1 = fmaf(Wh2[1 * HID_ + h], a, o1);
      o2 = fmaf(Wh2[2 * HID_ + h], a, o2);
    }
    float* dp = delta + ((size_t)gid * K_ + i) * 3;
    dp[0] = o0;
    dp[1] = o1;
    dp[2] = o2;
  }

  // ================= P2: fout = max_k(pe + gathered ht) =================
  // (no barrier needed before phase A: sfj/sout disjoint from sc)
  {
    const int lane = t & 63;
    const int w = t >> 6;                  // wave owns k-quarter w
    const int swz = lane & 31;
    const int wele = (lane >> 3) & 3;
    #pragma unroll 1
    for (int si = 0; si < 2; ++si) {
      const int n0 = n0b + si * 8;
      // phase A: gather fj -> swizzled LDS (lane = c, 256B coalesced reads)
      #pragma unroll
      for (int n = 0; n < 8; ++n) {
        const int* kn = knn + (size_t)(b * N_ + n0 + n) * K_ + w * 4;  // uniform
        #pragma unroll
        for (int kk = 0; kk < 4; ++kk) {
          const int id = kn[kk];
          const float hv = ht[(size_t)(b * N_ + id) * C_ + lane];
          sfj[lane * 128 + (((n * 4 + w) ^ swz) << 2) + (kk ^ wele)] = hv;
        }
      }
      __syncthreads();
      // phase B: pe read coalesced (2 c-rows x 512B per wave inst), nontemporal
      const int h = lane >> 5, sl = lane & 31;
      const int n = sl >> 2, j = sl & 3;
      #pragma unroll
      for (int it2 = 0; it2 < 8; ++it2) {
        const int c = it2 * 8 + w * 2 + h;
        const int px = it2 & 3;            // == (c>>3)&3, compile-time
        const f4 pv = __builtin_nontemporal_load(
            reinterpret_cast<const f4*>(pe + ((size_t)(b * C_ + c) * N_ + n0) * K_) + sl);
        const f4 fj = *reinterpret_cast<const f4*>(&sfj[c * 128 + ((sl ^ (c & 31)) << 2)]);
        float v = fmaxf(fmaxf(pv[0] + fj[0 ^ px], pv[1] + fj[1 ^ px]),
                        fmaxf(pv[2] + fj[2 ^ px], pv[3] + fj[3 ^ px]));
        v = fmaxf(v, __shfl_xor(v, 1));
        v = fmaxf(v, __shfl_xor(v, 2));
        if (j == 0) sout[c * 20 + si * 8 + n] = v;
      }
      __syncthreads();
    }
    // fout write: full 64B rows (float4 per thread)
    const int c = t >> 2, q = t & 3;
    const float4 r = *reinterpret_cast<const float4*>(&sout[c * 20 + q * 4]);
    *reinterpret_cast<float4*>(fout + (size_t)(b * C_ + c) * N_ + n0b + q * 4) = r;
  }
}

extern "C" void kernel_launch(void* const* d_in, const int* in_sizes, int n_in,
                              void* d_out, int out_size, void* d_ws, size_t ws_size,
                              hipStream_t stream) {
  // setup_inputs() dict order: p, f, pe, W1, b1, Wpe, bpe, Wh1, bh1, Wh2, bh2, knn_idx
  const float* p   = (const float*)d_in[0];
  const float* f   = (const float*)d_in[1];
  const float* pe  = (const float*)d_in[2];
  const float* W1  = (const float*)d_in[3];
  const float* b1  = (const float*)d_in[4];
  const float* Wpe = (const float*)d_in[5];
  const float* bpe = (const float*)d_in[6];
  const float* Wh1 = (const float*)d_in[7];
  const float* bh1 = (const float*)d_in[8];
  const float* Wh2 = (const float*)d_in[9];
  const float* bh2 = (const float*)d_in[10];
  const int* knn   = (const int*)d_in[11];
  float* fout  = (float*)d_out;                        // [B,C,N]
  float* delta = (float*)d_out + (size_t)B_ * C_ * N_; // [B*N,K,3]
  float* ht = (float*)d_ws;                            // [B,N,C] = 4 MB

  k1_conv<<<(B_ * N_) / 64, 256, 0, stream>>>(f, W1, b1, ht);
  k23<<<(B_ * N_) / 16, 256, 0, stream>>>(p, pe, ht, knn, Wpe, bpe, Wh1, bh1,
                                          Wh2, bh2, fout, delta);
}